// Round 1
// baseline (425.940 us; speedup 1.0000x reference)
//
#include <hip/hip_runtime.h>

// ResLSTM: B=4096 independent LSTM chains, T=512, H=32, scalar input per step.
// Mapping: one wave64 per batch element. Lane l computes gate rows l and l+64:
//   lanes 0..31:  row l    = i-gate,  row l+64 = g-gate
//   lanes 32..63: row l    = f-gate,  row l+64 = o-gate
// h[j] lives in lane j (j<32); broadcast to all lanes via v_readlane (SGPR
// operand into the FMA). No LDS, no __syncthreads — wave-synchronous.

static constexpr int T_LEN = 512;
static constexpr int H = 32;

__device__ __forceinline__ float rl(float v, int l) {
    return __int_as_float(__builtin_amdgcn_readlane(__float_as_int(v), l));
}

// sigmoid via v_exp_f32 + v_rcp_f32 (approx, ~1 ulp — far inside 3.4e-3 tol)
__device__ __forceinline__ float sigmoid_f(float x) {
    return __builtin_amdgcn_rcpf(1.0f + __expf(-x));
}

__global__ __launch_bounds__(256, 4)
void reslstm_kernel(const float* __restrict__ x,
                    const float* __restrict__ W_ih,
                    const float* __restrict__ W_hh,
                    const float* __restrict__ b_ih,
                    const float* __restrict__ b_hh,
                    const float* __restrict__ W_fc,
                    const float* __restrict__ b_fc,
                    float* __restrict__ out, int B)
{
    const int lane = threadIdx.x & 63;
    const int wv   = threadIdx.x >> 6;
    const int b    = (blockIdx.x << 2) + wv;
    if (b >= B) return;                       // wave-uniform guard

    const int r0 = lane;                      // i (lanes<32) or f (lanes>=32)
    const int r1 = lane + 64;                 // g (lanes<32) or o (lanes>=32)

    // W_hh rows for this lane -> registers (64 VGPRs). One-time, L1/L2 cached.
    float w0[H], w1[H];
    {
        const float4* v0 = reinterpret_cast<const float4*>(W_hh + r0 * H);
        const float4* v1 = reinterpret_cast<const float4*>(W_hh + r1 * H);
        #pragma unroll
        for (int q = 0; q < H / 4; ++q) {
            float4 a = v0[q], bb = v1[q];
            w0[4*q+0] = a.x;  w0[4*q+1] = a.y;  w0[4*q+2] = a.z;  w0[4*q+3] = a.w;
            w1[4*q+0] = bb.x; w1[4*q+1] = bb.y; w1[4*q+2] = bb.z; w1[4*q+3] = bb.w;
        }
    }
    const float wih0  = W_ih[r0];
    const float wih1  = W_ih[r1];
    const float bias0 = b_ih[r0] + b_hh[r0];
    const float bias1 = b_ih[r1] + b_hh[r1];

    // Branchless tanh-vs-sigmoid for the r1 gate: tanh(x) = 2*sigmoid(2x)-1.
    const bool  lo = (lane < 32);
    const float m1 = lo ? 2.0f : 1.0f;
    const float s1 = lo ? 2.0f : 1.0f;
    const float t1 = lo ? -1.0f : 0.0f;

    float h = 0.0f, c = 0.0f;
    const float* xrow = x + (size_t)b * T_LEN;

    for (int tc = 0; tc < T_LEN / 64; ++tc) {
        const float xv = xrow[(tc << 6) + lane];   // coalesced 64-float chunk
        #pragma unroll 2
        for (int tt = 0; tt < 64; ++tt) {
            const float xt = rl(xv, tt);           // x[b][t], wave-uniform
            float aA  = __builtin_fmaf(xt, wih0, bias0);
            float aB  = __builtin_fmaf(xt, wih1, bias1);
            float aA2 = 0.0f, aB2 = 0.0f;
            // matvec: 32 readlane broadcasts feeding 64 FMAs (2 acc chains
            // per row to halve dependent-FMA latency)
            #pragma unroll
            for (int k = 0; k < H; k += 2) {
                const float h0 = rl(h, k);
                const float h1 = rl(h, k + 1);
                aA  = __builtin_fmaf(w0[k],     h0, aA);
                aB  = __builtin_fmaf(w1[k],     h0, aB);
                aA2 = __builtin_fmaf(w0[k + 1], h1, aA2);
                aB2 = __builtin_fmaf(w1[k + 1], h1, aB2);
            }
            aA += aA2; aB += aB2;
            const float a0 = sigmoid_f(aA);                         // i | f
            const float a1 = __builtin_fmaf(s1, sigmoid_f(m1 * aB), t1); // g | o
            const float fo = __shfl_xor(a0, 32);   // lanes<32 get f[j]
            const float og = __shfl_xor(a1, 32);   // lanes<32 get o[j]
            // Only lanes<32 carry meaningful c,h; upper lanes compute bounded
            // garbage that is never read (readlane only touches lanes 0..31).
            c = __builtin_fmaf(fo, c, a0 * a1);                     // f*c + i*g
            const float th = __builtin_fmaf(2.0f, sigmoid_f(2.0f * c), -1.0f);
            h = og * th;                                            // o*tanh(c)
        }
    }

    // out[b] = sum_j h[j]*W_fc[j] + b_fc  (butterfly reduce over the wave)
    float val = lo ? h * W_fc[lane & (H - 1)] : 0.0f;
    #pragma unroll
    for (int off = 32; off >= 1; off >>= 1)
        val += __shfl_xor(val, off);
    if (lane == 0) out[b] = val + b_fc[0];
}

extern "C" void kernel_launch(void* const* d_in, const int* in_sizes, int n_in,
                              void* d_out, int out_size, void* d_ws, size_t ws_size,
                              hipStream_t stream) {
    const float* x    = (const float*)d_in[0];
    const float* W_ih = (const float*)d_in[1];
    const float* W_hh = (const float*)d_in[2];
    const float* b_ih = (const float*)d_in[3];
    const float* b_hh = (const float*)d_in[4];
    const float* W_fc = (const float*)d_in[5];
    const float* b_fc = (const float*)d_in[6];
    float* out = (float*)d_out;
    const int B = in_sizes[0] / T_LEN;        // 4096
    dim3 block(256);                          // 4 waves = 4 batch elements
    dim3 grid((B + 3) / 4);                   // 1024 blocks -> 4 waves/SIMD
    reslstm_kernel<<<grid, block, 0, stream>>>(x, W_ih, W_hh, b_ih, b_hh,
                                               W_fc, b_fc, out, B);
}

// Round 2
// 423.160 us; speedup vs baseline: 1.0066x; 1.0066x over previous
//
#include <hip/hip_runtime.h>

// ResLSTM: B=4096 independent LSTM chains, T=512, H=32, scalar input per step.
// Mapping: one wave64 per batch element. Lane l computes gate rows l and l+64:
//   lanes 0..31:  row l = i-gate,  row l+64 = g-gate
//   lanes 32..63: row l = f-gate,  row l+64 = o-gate
// h[j] lives in lane j (j<32); broadcast via constant-index v_readlane.
//
// R1 fix: W_hh weights held in 16 NAMED float4 variables (not indexed local
// arrays) so the register allocator cannot demote them to per-step reloads.
// R0 evidence: VGPR_Count=44 (< the 64 floats of weights) => weights were
// being re-fetched from L1 every step, ~85 extra instr/step, 407 us.

static constexpr int T_LEN = 512;
static constexpr int H = 32;

__device__ __forceinline__ float rl_c(float v, int l) {
    return __int_as_float(__builtin_amdgcn_readlane(__float_as_int(v), l));
}

// exp2-based sigmoid: sigmoid(x) = rcp(1 + exp2(x * -log2(e)))
__device__ __forceinline__ float sig_e2(float x_times_nlog2e) {
    return __builtin_amdgcn_rcpf(1.0f + __builtin_amdgcn_exp2f(x_times_nlog2e));
}

__global__ __launch_bounds__(256, 4)
void reslstm_kernel(const float* __restrict__ x,
                    const float* __restrict__ W_ih,
                    const float* __restrict__ W_hh,
                    const float* __restrict__ b_ih,
                    const float* __restrict__ b_hh,
                    const float* __restrict__ W_fc,
                    const float* __restrict__ b_fc,
                    float* __restrict__ out, int B)
{
    const int lane = threadIdx.x & 63;
    const int wv   = threadIdx.x >> 6;
    const int b    = (blockIdx.x << 2) + wv;
    if (b >= B) return;                       // wave-uniform guard

    const int r0 = lane;                      // i (lanes<32) or f (lanes>=32)
    const int r1 = lane + 64;                 // g (lanes<32) or o (lanes>=32)

    // W_hh rows for this lane -> 16 named float4 regs (64 VGPRs).
    const float4* pa = reinterpret_cast<const float4*>(W_hh + r0 * H);
    const float4* pb = reinterpret_cast<const float4*>(W_hh + r1 * H);
    const float4 a0 = pa[0], a1 = pa[1], a2 = pa[2], a3 = pa[3],
                 a4 = pa[4], a5 = pa[5], a6 = pa[6], a7 = pa[7];
    const float4 q0 = pb[0], q1 = pb[1], q2 = pb[2], q3 = pb[3],
                 q4 = pb[4], q5 = pb[5], q6 = pb[6], q7 = pb[7];

    const float wih0  = W_ih[r0];
    const float wih1  = W_ih[r1];
    const float bias0 = b_ih[r0] + b_hh[r0];
    const float bias1 = b_ih[r1] + b_hh[r1];

    // Branchless tanh-vs-sigmoid for the r1 gate: tanh(x) = 2*sigmoid(2x)-1.
    // Fold the sigmoid's -log2(e) and the 2x into per-lane constants.
    const bool  lo = (lane < 32);
    constexpr float NL2E = -1.4426950408889634f;
    const float e1 = lo ? 2.0f * NL2E : NL2E;  // exp2 arg scale for gate r1
    const float s1 = lo ? 2.0f : 1.0f;
    const float t1 = lo ? -1.0f : 0.0f;

    float h = 0.0f, c = 0.0f;
    const float* xrow = x + (size_t)b * T_LEN;

#define MAC4(va, vq, K)                                                   \
    {                                                                     \
        const float h0 = rl_c(h, (K) + 0);                                \
        const float h1 = rl_c(h, (K) + 1);                                \
        const float h2 = rl_c(h, (K) + 2);                                \
        const float h3 = rl_c(h, (K) + 3);                                \
        aA  = __builtin_fmaf(va.x, h0, aA);                               \
        aB  = __builtin_fmaf(vq.x, h0, aB);                               \
        aA2 = __builtin_fmaf(va.y, h1, aA2);                              \
        aB2 = __builtin_fmaf(vq.y, h1, aB2);                              \
        aA  = __builtin_fmaf(va.z, h2, aA);                               \
        aB  = __builtin_fmaf(vq.z, h2, aB);                               \
        aA2 = __builtin_fmaf(va.w, h3, aA2);                              \
        aB2 = __builtin_fmaf(vq.w, h3, aB2);                              \
    }

    for (int tc = 0; tc < T_LEN / 64; ++tc) {
        const float xv = xrow[(tc << 6) + lane];   // coalesced 64-float chunk
        #pragma unroll 4
        for (int tt = 0; tt < 64; ++tt) {
            const float xt = rl_c(xv, tt);         // x[b][t], wave-uniform
            float aA  = __builtin_fmaf(xt, wih0, bias0);
            float aB  = __builtin_fmaf(xt, wih1, bias1);
            float aA2 = 0.0f, aB2 = 0.0f;
            MAC4(a0, q0, 0)  MAC4(a1, q1, 4)  MAC4(a2, q2, 8)  MAC4(a3, q3, 12)
            MAC4(a4, q4, 16) MAC4(a5, q5, 20) MAC4(a6, q6, 24) MAC4(a7, q7, 28)
            aA += aA2; aB += aB2;
            const float g0 = sig_e2(aA * NL2E);                    // i | f
            const float g1 = __builtin_fmaf(s1, sig_e2(aB * e1), t1); // g | o
            const float fo = __shfl_xor(g0, 32);   // lanes<32 get f[j]
            const float og = __shfl_xor(g1, 32);   // lanes<32 get o[j]
            // Only lanes<32 carry meaningful c,h; upper lanes compute bounded
            // garbage never read (h-readlanes touch lanes 0..31 only).
            c = __builtin_fmaf(fo, c, g0 * g1);                    // f*c + i*g
            const float th = __builtin_fmaf(2.0f, sig_e2(c * (2.0f * NL2E)), -1.0f);
            h = og * th;                                           // o*tanh(c)
        }
    }
#undef MAC4

    // out[b] = sum_j h[j]*W_fc[j] + b_fc  (butterfly reduce over the wave)
    float val = lo ? h * W_fc[lane & (H - 1)] : 0.0f;
    #pragma unroll
    for (int off = 32; off >= 1; off >>= 1)
        val += __shfl_xor(val, off);
    if (lane == 0) out[b] = val + b_fc[0];
}

extern "C" void kernel_launch(void* const* d_in, const int* in_sizes, int n_in,
                              void* d_out, int out_size, void* d_ws, size_t ws_size,
                              hipStream_t stream) {
    const float* x    = (const float*)d_in[0];
    const float* W_ih = (const float*)d_in[1];
    const float* W_hh = (const float*)d_in[2];
    const float* b_ih = (const float*)d_in[3];
    const float* b_hh = (const float*)d_in[4];
    const float* W_fc = (const float*)d_in[5];
    const float* b_fc = (const float*)d_in[6];
    float* out = (float*)d_out;
    const int B = in_sizes[0] / T_LEN;        // 4096
    dim3 block(256);                          // 4 waves = 4 batch elements
    dim3 grid((B + 3) / 4);                   // 1024 blocks -> 4 waves/SIMD
    reslstm_kernel<<<grid, block, 0, stream>>>(x, W_ih, W_hh, b_ih, b_hh,
                                               W_fc, b_fc, out, B);
}